// Round 2
// baseline (2368.136 us; speedup 1.0000x reference)
//
#include <hip/hip_runtime.h>

// GNN2: 3-layer GAT over 16384 independent 32-node cliques. f32 I/O, f32 compute.
// One block of 256 threads per graph.

#define GS 132   // LDS row stride (128 + 4 pad)

// One GAT layer: bufA[32][FIN] -> (GEMM) bufB[32][4D] -> (attn+aggregate) bufA[32][4D]
template<int FIN, int D>
__device__ __forceinline__ void gat_layer(
    int t,
    const float* __restrict__ Wf,       // [FIN][4*D] row-major
    const float* __restrict__ asrc,     // [4*D]
    const float* __restrict__ adst,     // [4*D]
    const float* __restrict__ bias,     // [4*D]
    float (*bufA)[GS], float (*bufB)[GS],
    float* ssrc, float* sdst)           // [32*4] each
{
    constexpr int FOUT = 4 * D;
    constexpr int CPT  = FOUT / 8;      // cols per thread (16,16,3)

    // ---- GEMM: bufB = bufA @ W ----
    {
        int i  = t >> 3;
        int c0 = (t & 7) * CPT;
        float acc[CPT];
        #pragma unroll
        for (int c = 0; c < CPT; ++c) acc[c] = 0.f;
        for (int k = 0; k < FIN; ++k) {
            float a = bufA[i][k];
            #pragma unroll
            for (int c = 0; c < CPT; ++c)
                acc[c] = fmaf(a, Wf[k * FOUT + c0 + c], acc[c]);
        }
        #pragma unroll
        for (int c = 0; c < CPT; ++c) bufB[i][c0 + c] = acc[c];
    }
    __syncthreads();

    // ---- attention coefficients per (node j, head hd) ----
    if (t < 128) {
        int j = t >> 2, hd = t & 3;
        float s1 = 0.f, s2 = 0.f;
        for (int d = 0; d < D; ++d) {
            float hv = bufB[j][hd * D + d];
            s1 = fmaf(hv, asrc[hd * D + d], s1);
            s2 = fmaf(hv, adst[hd * D + d], s2);
        }
        ssrc[j * 4 + hd] = s1;
        sdst[j * 4 + hd] = s2;
    }
    __syncthreads();

    // ---- fused softmax + aggregation: bufA[i] = softmax_j(lrelu(sd_i+ss_j)) @ bufB ----
    {
        constexpr int DH = D / 2;
        int p = t >> 1, half = t & 1;
        int i = p >> 2, hd = p & 3;
        int d0 = hd * D + half * DH;
        float sd = sdst[i * 4 + hd];

        float m = -1e30f;
        for (int j = 0; j < 32; ++j) {
            float e = sd + ssrc[j * 4 + hd];
            e = e > 0.f ? e : 0.2f * e;
            m = fmaxf(m, e);
        }
        float sum = 0.f;
        float acc[DH];
        #pragma unroll
        for (int d = 0; d < DH; ++d) acc[d] = 0.f;
        for (int j = 0; j < 32; ++j) {
            float e = sd + ssrc[j * 4 + hd];
            e = e > 0.f ? e : 0.2f * e;
            float w = __expf(e - m);
            sum += w;
            #pragma unroll
            for (int d = 0; d < DH; ++d)
                acc[d] = fmaf(w, bufB[j][d0 + d], acc[d]);
        }
        float inv = 1.f / sum;
        #pragma unroll
        for (int d = 0; d < DH; ++d)
            bufA[i][d0 + d] = acc[d] * inv + bias[d0 + d];
    }
    __syncthreads();
}

__global__ __launch_bounds__(256) void gat_main(
    const float* __restrict__ xs,    // [B*R*32]
    const float* __restrict__ pe,    // [B*32*15]
    const float* __restrict__ W1, const float* __restrict__ as1,
    const float* __restrict__ ad1, const float* __restrict__ b1,
    const float* __restrict__ W2, const float* __restrict__ as2,
    const float* __restrict__ ad2, const float* __restrict__ b2,
    const float* __restrict__ W3, const float* __restrict__ as3,
    const float* __restrict__ ad3, const float* __restrict__ b3,
    const float* __restrict__ LW, const float* __restrict__ lb,
    float* __restrict__ out,         // [B*R*64]
    int R)
{
    __shared__ float bufA[32][GS];
    __shared__ float bufB[32][GS];
    __shared__ float ssrc[128], sdst[128], mcol[24];

    int t = threadIdx.x;
    int g = blockIdx.x;
    int b = g / R;

    // build x[32][16]: col 0 = cell scalar, cols 1..15 = pos enc
    for (int idx = t; idx < 512; idx += 256) {
        int j = idx >> 4, k = idx & 15;
        float v = (k == 0) ? xs[g * 32 + j]
                           : pe[b * 480 + j * 15 + (k - 1)];
        bufA[j][k] = v;
    }
    __syncthreads();

    gat_layer<16, 32>(t, W1, as1, ad1, b1, bufA, bufB, ssrc, sdst);
    gat_layer<128, 32>(t, W2, as2, ad2, b2, bufA, bufB, ssrc, sdst);
    gat_layer<128, 6>(t, W3, as3, ad3, b3, bufA, bufB, ssrc, sdst);

    // mean over nodes, then 24->64 linear
    if (t < 24) {
        float s = 0.f;
        for (int i = 0; i < 32; ++i) s += bufA[i][t];
        mcol[t] = s * (1.f / 32.f);
    }
    __syncthreads();
    if (t < 64) {
        float o = lb[t];
        for (int c = 0; c < 24; ++c)
            o = fmaf(mcol[c], LW[c * 64 + t], o);
        out[g * 64 + t] = o;
    }
}

extern "C" void kernel_launch(void* const* d_in, const int* in_sizes, int n_in,
                              void* d_out, int out_size, void* d_ws, size_t ws_size,
                              hipStream_t stream) {
    const float* xs  = (const float*)d_in[0];
    const float* pe  = (const float*)d_in[1];
    const float* W1  = (const float*)d_in[2];
    const float* as1 = (const float*)d_in[3];
    const float* ad1 = (const float*)d_in[4];
    const float* b1  = (const float*)d_in[5];
    const float* W2  = (const float*)d_in[6];
    const float* as2 = (const float*)d_in[7];
    const float* ad2 = (const float*)d_in[8];
    const float* b2  = (const float*)d_in[9];
    const float* W3  = (const float*)d_in[10];
    const float* as3 = (const float*)d_in[11];
    const float* ad3 = (const float*)d_in[12];
    const float* b3  = (const float*)d_in[13];
    const float* LW  = (const float*)d_in[14];
    const float* lb  = (const float*)d_in[15];
    float* o = (float*)d_out;

    int G = in_sizes[0] / 32;       // B*R graphs
    int B = in_sizes[1] / 480;      // pos_enc = B*32*15
    int R = G / B;

    gat_main<<<dim3(G), dim3(256), 0, stream>>>(xs, pe,
                                                W1, as1, ad1, b1,
                                                W2, as2, ad2, b2,
                                                W3, as3, ad3, b3,
                                                LW, lb, o, R);
}

// Round 4
// 229.104 us; speedup vs baseline: 10.3365x; 10.3365x over previous
//
#include <hip/hip_runtime.h>
#include <hip/hip_bf16.h>

// GNN2: 3-layer GAT over 16384 independent 32-node cliques.
// One WAVE per graph (4 graphs / 256-thread block), zero barriers.
// GEMMs + attention-aggregation on mfma_f32_16x16x32_bf16; scores fused into
// the GEMM via pre-multiplied Wa = W @ [a_src|a_dst] columns. f32 accumulate.

typedef __attribute__((ext_vector_type(8))) short short8;
typedef __attribute__((ext_vector_type(4))) short short4v;
typedef __attribute__((ext_vector_type(4))) float f32x4;
typedef __attribute__((ext_vector_type(2))) float f32x2;

#define MFMA16(a,b,c) __builtin_amdgcn_mfma_f32_16x16x32_bf16(a,b,c,0,0,0)

__device__ __forceinline__ short f2bf(float f) {
    __hip_bfloat16 h = __float2bfloat16(f);
    return *reinterpret_cast<short*>(&h);
}

// ---------------- pre-kernel: build transposed bf16 weights in ws ----------------
// ws layout (bf16 elements):
//  [0,4608)      W1T [144][32]   rows n: n<128 -> W1[k][n] (k<16, rest 0);
//                                n in 128..135 -> Wa1 col (n-128); 136..143 -> 0
//  [4608,23040)  W2T [144][128]  same scheme for W2/Wa2
//  [23040,33280) W3T [80][128]   n<64: hd=n>>4, dl=n&15, dl<6 -> W3[k][hd*6+dl] else 0;
//                                n in 64..71 -> Wa3; 72..79 -> 0
__global__ __launch_bounds__(256) void build_wt(
    const float* __restrict__ W1, const float* __restrict__ as1, const float* __restrict__ ad1,
    const float* __restrict__ W2, const float* __restrict__ as2, const float* __restrict__ ad2,
    const float* __restrict__ W3, const float* __restrict__ as3, const float* __restrict__ ad3,
    short* __restrict__ ws)
{
    int i = blockIdx.x * 256 + threadIdx.x;
    float val = 0.f;
    if (i < 4608) {
        int n = i >> 5, k = i & 31;
        if (k < 16) {
            if (n < 128) val = W1[k*128 + n];
            else if (n < 136) {
                int cc = n - 128; const float* a = (cc < 4) ? as1 : ad1;
                for (int dl = 0; dl < 32; ++dl)
                    val += W1[k*128 + (cc&3)*32 + dl] * a[(cc&3)*32 + dl];
            }
        }
        ws[i] = f2bf(val);
    } else if (i < 23040) {
        int j = i - 4608; int n = j >> 7, k = j & 127;
        if (n < 128) val = W2[k*128 + n];
        else if (n < 136) {
            int cc = n - 128; const float* a = (cc < 4) ? as2 : ad2;
            for (int dl = 0; dl < 32; ++dl)
                val += W2[k*128 + (cc&3)*32 + dl] * a[(cc&3)*32 + dl];
        }
        ws[i] = f2bf(val);
    } else {
        int j = i - 23040; int n = j >> 7, k = j & 127;
        if (n < 64) {
            int hd = n >> 4, dl = n & 15;
            if (dl < 6) val = W3[k*24 + hd*6 + dl];
        } else if (n < 72) {
            int cc = n - 64; const float* a = (cc < 4) ? as3 : ad3;
            for (int dl = 0; dl < 6; ++dl)
                val += W3[k*24 + (cc&3)*6 + dl] * a[(cc&3)*6 + dl];
        }
        ws[i] = f2bf(val);
    }
}

// ---------------- main-kernel phases ----------------
// Fragment layout (gfx950 16x16x32 bf16): A: row=lane&15, k=8*(lane>>4)+v;
// B: col=lane&15, k=8*(lane>>4)+v; D: col=lane&15, row=4*(lane>>4)+r. [m89/m93]

// GEMM: acc[mt][nt] = xb[32][K] @ WT; xb stride 136 bf16 (272B, bank-uniform, 16B-aligned).
template<int KC, int NT>
__device__ __forceinline__ void gemm_phase(const short* xb, const short* wtL,
                                           int c, int q, f32x4 (&acc)[2][NT])
{
    short8 afr[2][KC];                       // preload ALL A-frags (xb region gets reused)
    #pragma unroll
    for (int mt = 0; mt < 2; ++mt)
      #pragma unroll
      for (int kc = 0; kc < KC; ++kc)
        afr[mt][kc] = *(const short8*)&xb[(mt*16 + c)*136 + kc*32 + q*8];
    #pragma unroll
    for (int mt = 0; mt < 2; ++mt)
      #pragma unroll
      for (int nt = 0; nt < NT; ++nt)
        acc[mt][nt] = (f32x4){0.f, 0.f, 0.f, 0.f};
    #pragma unroll
    for (int kc = 0; kc < KC; ++kc)
      #pragma unroll
      for (int nt = 0; nt < NT; ++nt) {
        short8 bfr = *(const short8*)&wtL[(nt*16 + c)*(KC*32) + kc*32 + q*8];
        #pragma unroll
        for (int mt = 0; mt < 2; ++mt)
          acc[mt][nt] = MFMA16(afr[mt][kc], bfr, acc[mt][nt]);
      }
}

// Write h transposed (ht[d][j], stride 32 bf16, packed b64) + dump score cols to ss.
template<int NTH, int NT>
__device__ __forceinline__ void write_ht_scores(const f32x4 (&acc)[2][NT],
                                                short* ht, float* ss, int c, int q)
{
    #pragma unroll
    for (int nt = 0; nt < NTH; ++nt)
      #pragma unroll
      for (int mt = 0; mt < 2; ++mt) {
        short4v hv;
        #pragma unroll
        for (int r = 0; r < 4; ++r) hv[r] = f2bf(acc[mt][nt][r]);
        *(short4v*)&ht[(nt*16 + c)*32 + mt*16 + q*4] = hv;
      }
    if (c < 8) {                              // score tile: c<4 = s_src head c, c>=4 = s_dst
      #pragma unroll
      for (int mt = 0; mt < 2; ++mt)
        #pragma unroll
        for (int r = 0; r < 4; ++r)
          ss[c*36 + mt*16 + q*4 + r] = acc[mt][NT-1][r];
    }
}

// Per-(head,i) softmax stats: m_i = lrelu(sd_i + max_j ss_j), rden = 1/sum exp.
__device__ __forceinline__ void stats_phase(const float* ss, float* st, int lane)
{
    #pragma unroll
    for (int pp = 0; pp < 2; ++pp) {
        int p = lane + pp*64;
        int hd = p >> 5, ii = p & 31;
        float sv[32];
        #pragma unroll
        for (int jj = 0; jj < 32; jj += 4) {
            f32x4 v4 = *(const f32x4*)&ss[hd*36 + jj];
            sv[jj] = v4[0]; sv[jj+1] = v4[1]; sv[jj+2] = v4[2]; sv[jj+3] = v4[3];
        }
        float sd = ss[(4+hd)*36 + ii];
        float M = sv[0];
        #pragma unroll
        for (int jj = 1; jj < 32; ++jj) M = fmaxf(M, sv[jj]);
        float m = sd + M; m = fmaxf(m, 0.2f*m);       // lrelu is monotone
        float den = 0.f;
        #pragma unroll
        for (int jj = 0; jj < 32; ++jj) {
            float e = sd + sv[jj]; e = fmaxf(e, 0.2f*e);
            den += __expf(e - m);
        }
        f32x2 o; o[0] = m; o[1] = 1.0f / den;
        *(f32x2*)&st[(hd*32 + ii)*2] = o;
    }
}

// Build P directly in agg-B-fragment layout: lane holds P[i = nt*16+c][j = q*8+v].
__device__ __forceinline__ void frag_phase(const float* ss, const float* st,
                                           int c, int q, short8 (&pfr)[4][2])
{
    #pragma unroll
    for (int hd = 0; hd < 4; ++hd) {
        f32x4 s0 = *(const f32x4*)&ss[hd*36 + q*8];
        f32x4 s1 = *(const f32x4*)&ss[hd*36 + q*8 + 4];
        #pragma unroll
        for (int nt = 0; nt < 2; ++nt) {
            int ii = nt*16 + c;
            f32x2 ms = *(const f32x2*)&st[(hd*32 + ii)*2];
            float sd = ss[(4+hd)*36 + ii];
            short8 pf;
            #pragma unroll
            for (int v = 0; v < 8; ++v) {
                float sj = (v < 4) ? s0[v] : s1[v-4];
                float e = sd + sj; e = fmaxf(e, 0.2f*e);
                pf[v] = f2bf(__expf(e - ms[0]) * ms[1]);
            }
            pfr[hd][nt] = pf;
        }
    }
}

// Aggregation: out^T[d][i] = sum_j ht[d][j] * P[i][j]; head = mt >> HDSH.
template<int AGGMT, int HDSH>
__device__ __forceinline__ void agg_phase(const short* ht, const short8 (&pfr)[4][2],
                                          int c, int q, f32x4 (&acc)[AGGMT][2])
{
    const f32x4 zf = {0.f, 0.f, 0.f, 0.f};
    short8 afr[AGGMT];                        // preload (ht region gets overwritten next)
    #pragma unroll
    for (int mt = 0; mt < AGGMT; ++mt)
        afr[mt] = *(const short8*)&ht[(mt*16 + c)*32 + q*8];
    #pragma unroll
    for (int mt = 0; mt < AGGMT; ++mt)
      #pragma unroll
      for (int nt = 0; nt < 2; ++nt)
        acc[mt][nt] = MFMA16(afr[mt], pfr[mt >> HDSH][nt], zf);
}

// Layer transition: xb[i][d] = agg + bias[d], packed b64 writes (4 consecutive d).
__device__ __forceinline__ void trans_phase(const f32x4 (&acc)[8][2], const float* bias,
                                            short* xb, int c, int q)
{
    #pragma unroll
    for (int mt = 0; mt < 8; ++mt) {
        f32x4 bv = *(const f32x4*)&bias[mt*16 + q*4];
        #pragma unroll
        for (int nt = 0; nt < 2; ++nt) {
            int ii = nt*16 + c;
            short4v o;
            #pragma unroll
            for (int r = 0; r < 4; ++r) o[r] = f2bf(acc[mt][nt][r] + bv[r]);
            *(short4v*)&xb[ii*136 + mt*16 + q*4] = o;
        }
    }
}

__global__ __launch_bounds__(256) void gat_mfma(
    const float* __restrict__ xs, const float* __restrict__ pe,
    const short* __restrict__ ws,
    const float* __restrict__ b1, const float* __restrict__ b2, const float* __restrict__ b3,
    const float* __restrict__ LW, const float* __restrict__ lb,
    float* __restrict__ out, int R)
{
    __shared__ short buf[4][4352];      // per-wave union: xb[32][136] <-> ht[128][32]
    __shared__ float sldsA[4][8*36];    // score cols: [8][36] f32
    __shared__ float statsA[4][256];    // [4 hd][32 i][{m, rden}]
    __shared__ float mcol[4][32];       // per-graph column means (24 used)

    int t = threadIdx.x;
    int w = t >> 6, lane = t & 63;
    int c = lane & 15, q = lane >> 4;
    int g = blockIdx.x * 4 + w;
    int b = g / R;

    short* xb = buf[w];
    short* ht = buf[w];
    float* ss = sldsA[w];
    float* st = statsA[w];

    // ---- build x0 [32][16] bf16 (cols 16..31 zero-padded for K=32 MFMA) ----
    {
        int j = lane >> 1, half = lane & 1;
        float v[8];
        if (half == 0) {
            v[0] = xs[g*32 + j];
            #pragma unroll
            for (int kk = 0; kk < 7; ++kk) v[1+kk] = pe[b*480 + j*15 + kk];
        } else {
            #pragma unroll
            for (int kk = 0; kk < 8; ++kk) v[kk] = pe[b*480 + j*15 + 7 + kk];
        }
        short8 px;
        #pragma unroll
        for (int kk = 0; kk < 8; ++kk) px[kk] = f2bf(v[kk]);
        *(short8*)&xb[j*136 + half*8] = px;
        *(short8*)&xb[j*136 + 16 + half*8] = (short8){0,0,0,0,0,0,0,0};
    }

    const short* wt1 = ws;
    const short* wt2 = ws + 4608;
    const short* wt3 = ws + 23040;

    // ================= layer 1 (K=16 padded to 32, N = 128 h + 8 score) ===========
    {
        f32x4 acc[2][9];
        gemm_phase<1,9>(xb, wt1, c, q, acc);
        write_ht_scores<8,9>(acc, ht, ss, c, q);
        stats_phase(ss, st, lane);
        short8 pfr[4][2];
        frag_phase(ss, st, c, q, pfr);
        f32x4 agg[8][2];
        agg_phase<8,1>(ht, pfr, c, q, agg);
        trans_phase(agg, b1, xb, c, q);
    }
    // ================= layer 2 (K=128) ============================================
    {
        f32x4 acc[2][9];
        gemm_phase<4,9>(xb, wt2, c, q, acc);
        write_ht_scores<8,9>(acc, ht, ss, c, q);
        stats_phase(ss, st, lane);
        short8 pfr[4][2];
        frag_phase(ss, st, c, q, pfr);
        f32x4 agg[8][2];
        agg_phase<8,1>(ht, pfr, c, q, agg);
        trans_phase(agg, b2, xb, c, q);
    }
    // ================= layer 3 (out dim 24, head-padded to 4x16) ==================
    {
        f32x4 acc[2][5];
        gemm_phase<4,5>(xb, wt3, c, q, acc);
        write_ht_scores<4,5>(acc, ht, ss, c, q);
        stats_phase(ss, st, lane);
        short8 pfr[4][2];
        frag_phase(ss, st, c, q, pfr);
        f32x4 agg[4][2];
        agg_phase<4,0>(ht, pfr, c, q, agg);

        // mean over nodes i: in-lane nt add, then butterfly over c bits
        float red[4][4];
        #pragma unroll
        for (int mt = 0; mt < 4; ++mt)
          #pragma unroll
          for (int r = 0; r < 4; ++r)
            red[mt][r] = agg[mt][0][r] + agg[mt][1][r];
        #pragma unroll
        for (int m = 1; m < 16; m <<= 1)
          #pragma unroll
          for (int mt = 0; mt < 4; ++mt)
            #pragma unroll
            for (int r = 0; r < 4; ++r)
              red[mt][r] += __shfl_xor(red[mt][r], m, 64);
        if (c == 0) {
          #pragma unroll
          for (int mt = 0; mt < 4; ++mt)
            #pragma unroll
            for (int r = 0; r < 4; ++r) {
              int dl = q*4 + r;                       // real only for dl < 6
              if (dl < 6)
                mcol[w][mt*6 + dl] = red[mt][r] * (1.f/32.f) + b3[mt*6 + dl];
            }
        }
    }
    // ---- epilogue: out[g] = mcol @ lin_w + lin_b (f32) ----
    {
        float o = lb[lane];
        #pragma unroll
        for (int cc = 0; cc < 24; ++cc)
            o = fmaf(mcol[w][cc], LW[cc*64 + lane], o);
        out[g*64 + lane] = o;
    }
}

extern "C" void kernel_launch(void* const* d_in, const int* in_sizes, int n_in,
                              void* d_out, int out_size, void* d_ws, size_t ws_size,
                              hipStream_t stream) {
    const float* xs  = (const float*)d_in[0];
    const float* pe  = (const float*)d_in[1];
    const float* W1  = (const float*)d_in[2];
    const float* as1 = (const float*)d_in[3];
    const float* ad1 = (const float*)d_in[4];
    const float* b1  = (const float*)d_in[5];
    const float* W2  = (const float*)d_in[6];
    const float* as2 = (const float*)d_in[7];
    const float* ad2 = (const float*)d_in[8];
    const float* b2  = (const float*)d_in[9];
    const float* W3  = (const float*)d_in[10];
    const float* as3 = (const float*)d_in[11];
    const float* ad3 = (const float*)d_in[12];
    const float* b3  = (const float*)d_in[13];
    const float* LW  = (const float*)d_in[14];
    const float* lb  = (const float*)d_in[15];
    float* o = (float*)d_out;
    short* ws = (short*)d_ws;

    int G = in_sizes[0] / 32;       // B*R graphs (16384)
    int B = in_sizes[1] / 480;      // pos_enc = B*32*15
    int R = G / B;

    build_wt<<<dim3(130), dim3(256), 0, stream>>>(W1, as1, ad1, W2, as2, ad2,
                                                  W3, as3, ad3, ws);
    gat_mfma<<<dim3(G/4), dim3(256), 0, stream>>>(xs, pe, ws, b1, b2, b3, LW, lb, o, R);
}

// Round 5
// 138.082 us; speedup vs baseline: 17.1503x; 1.6592x over previous
//
#include <hip/hip_runtime.h>
#include <hip/hip_bf16.h>

// GNN2: 3-layer GAT over 16384 independent 32-node cliques.
// One WAVE per graph (4 graphs / 256-thread block), zero barriers.
// GEMMs + attention-aggregation on mfma_f32_16x16x32_bf16; scores fused into
// the GEMM via pre-multiplied Wa = W @ [a_src|a_dst] columns. f32 accumulate.
// den computed in-frag (+2 shfl), normalization folded into trans (fmaf rden).
// ht XOR-swizzled (granule ^ d&7) to kill LDS bank conflicts. 39 KB LDS -> 4 blk/CU.

typedef __attribute__((ext_vector_type(8))) short short8;
typedef __attribute__((ext_vector_type(4))) short short4v;
typedef __attribute__((ext_vector_type(4))) float f32x4;

#define MFMA16(a,b,c) __builtin_amdgcn_mfma_f32_16x16x32_bf16(a,b,c,0,0,0)

__device__ __forceinline__ short f2bf(float f) {
    __hip_bfloat16 h = __float2bfloat16(f);
    return *reinterpret_cast<short*>(&h);
}

// ---------------- pre-kernel: tiled transposed bf16 weights in ws ----------------
// Tile layout per layer: [nt][kc][16][32] bf16 — B-frag loads are 1KB contiguous/wave.
//  wt1 [0,4608):       NT=9, KC=1. n=nt*16+c: n<128 -> W1[k][n] (k<16 else 0);
//                      n in 128..135 -> Wa1 col (n-128); else 0
//  wt2 [4608,23040):   NT=9, KC=4. same scheme for W2/Wa2
//  wt3 [23040,33280):  NT=5, KC=4. n<64: hd=n>>4, dl=n&15, dl<6 -> W3[k][hd*6+dl] else 0;
//                      n in 64..71 -> Wa3; else 0
__global__ __launch_bounds__(256) void build_wt(
    const float* __restrict__ W1, const float* __restrict__ as1, const float* __restrict__ ad1,
    const float* __restrict__ W2, const float* __restrict__ as2, const float* __restrict__ ad2,
    const float* __restrict__ W3, const float* __restrict__ as3, const float* __restrict__ ad3,
    short* __restrict__ ws)
{
    int i = blockIdx.x * 256 + threadIdx.x;
    float val = 0.f;
    if (i < 4608) {                       // layer 1 (KC=1 -> degenerates to [n][k])
        int n = i >> 5, k = i & 31;
        if (k < 16) {
            if (n < 128) val = W1[k*128 + n];
            else if (n < 136) {
                int cc = n - 128; const float* a = (cc < 4) ? as1 : ad1;
                for (int dl = 0; dl < 32; ++dl)
                    val += W1[k*128 + (cc&3)*32 + dl] * a[(cc&3)*32 + dl];
            }
        }
        ws[i] = f2bf(val);
    } else if (i < 23040) {               // layer 2
        int j = i - 4608;
        int kq = j & 31, c = (j >> 5) & 15, kc = (j >> 9) & 3, nt = j >> 11;
        int n = nt*16 + c, k = kc*32 + kq;
        if (n < 128) val = W2[k*128 + n];
        else if (n < 136) {
            int cc = n - 128; const float* a = (cc < 4) ? as2 : ad2;
            for (int dl = 0; dl < 32; ++dl)
                val += W2[k*128 + (cc&3)*32 + dl] * a[(cc&3)*32 + dl];
        }
        ws[i] = f2bf(val);
    } else {                              // layer 3
        int j = i - 23040;
        int kq = j & 31, c = (j >> 5) & 15, kc = (j >> 9) & 3, nt = j >> 11;
        int n = nt*16 + c, k = kc*32 + kq;
        if (n < 64) {
            int hd = n >> 4, dl = n & 15;
            if (dl < 6) val = W3[k*24 + hd*6 + dl];
        } else if (n < 72) {
            int cc = n - 64; const float* a = (cc < 4) ? as3 : ad3;
            for (int dl = 0; dl < 6; ++dl)
                val += W3[k*24 + (cc&3)*6 + dl] * a[(cc&3)*6 + dl];
        }
        ws[i] = f2bf(val);
    }
}

// ---------------- main-kernel phases ----------------
// Fragment layout (gfx950 16x16x32 bf16): A: row=lane&15, k=8*(lane>>4)+v;
// B: col=lane&15, k=8*(lane>>4)+v; D: col=lane&15, row=4*(lane>>4)+r. [m89/m93]

// GEMM: acc[mt][nt] = xb[32][KC*32] @ W; streaming frag loads (low VGPR).
template<int KC, int NT>
__device__ __forceinline__ void gemm_phase(const short* xb, const short* wt,
                                           int c, int q, f32x4 (&acc)[2][NT])
{
    #pragma unroll
    for (int mt = 0; mt < 2; ++mt)
      #pragma unroll
      for (int nt = 0; nt < NT; ++nt)
        acc[mt][nt] = (f32x4){0.f, 0.f, 0.f, 0.f};
    #pragma unroll
    for (int kc = 0; kc < KC; ++kc) {
        short8 a0 = *(const short8*)&xb[c*136        + kc*32 + q*8];
        short8 a1 = *(const short8*)&xb[(16+c)*136   + kc*32 + q*8];
        #pragma unroll
        for (int nt = 0; nt < NT; ++nt) {
            short8 bfr = *(const short8*)&wt[((nt*KC + kc)*16 + c)*32 + q*8];
            acc[0][nt] = MFMA16(a0, bfr, acc[0][nt]);
            acc[1][nt] = MFMA16(a1, bfr, acc[1][nt]);
        }
    }
}

// Write h^T (ht[d][j], stride 32, granule-XOR-swizzled) + score cols (f32x4) to ss.
template<int NTH, int NT>
__device__ __forceinline__ void write_ht_scores(const f32x4 (&acc)[2][NT],
                                                short* ht, float* ss, int c, int q)
{
    #pragma unroll
    for (int nt = 0; nt < NTH; ++nt) {
      int d = nt*16 + c;
      #pragma unroll
      for (int mt = 0; mt < 2; ++mt) {
        short4v hv;
        #pragma unroll
        for (int r = 0; r < 4; ++r) hv[r] = f2bf(acc[mt][nt][r]);
        int g8 = (4*mt + q) ^ (c & 7);           // swizzled 8B granule
        *(short4v*)&ht[d*32 + g8*4] = hv;
      }
    }
    if (c < 8) {          // score tile: rows c<4 = s_src head c, c>=4 = s_dst
      #pragma unroll
      for (int mt = 0; mt < 2; ++mt)
        *(f32x4*)&ss[c*32 + mt*16 + q*4] = acc[mt][NT-1];
    }
}

// Per-head source max: M[hd] = max_j s_src[hd][j] (exact softmax max via monotone lrelu).
__device__ __forceinline__ void max_phase(const float* ss, float* Msh, int lane)
{
    int hd2 = lane >> 4, jj = lane & 15;
    float v = fmaxf(ss[hd2*32 + jj], ss[hd2*32 + 16 + jj]);
    #pragma unroll
    for (int m = 1; m < 16; m <<= 1)
        v = fmaxf(v, __shfl_xor(v, m, 64));
    if (jj == 0) Msh[hd2] = v;
}

// Build unnormalized P in B-frag layout + per-(hd,i) 1/den via q-bit shfl reduce.
__device__ __forceinline__ void frag_phase(const float* ss, const float* Msh,
                                           int c, int q, short8 (&pfr)[4][2],
                                           float (&rden)[4][2])
{
    #pragma unroll
    for (int hd = 0; hd < 4; ++hd) {
        float Mh = Msh[hd];
        f32x4 s0 = *(const f32x4*)&ss[hd*32 + q*8];
        f32x4 s1 = *(const f32x4*)&ss[hd*32 + q*8 + 4];
        #pragma unroll
        for (int nt = 0; nt < 2; ++nt) {
            float sd = ss[(4+hd)*32 + nt*16 + c];
            float m = sd + Mh; m = fmaxf(m, 0.2f*m);   // = max_j lrelu(sd+ss_j)
            float den = 0.f;
            short8 pf;
            #pragma unroll
            for (int v = 0; v < 8; ++v) {
                float sj = (v < 4) ? s0[v] : s1[v-4];
                float e = sd + sj; e = fmaxf(e, 0.2f*e);
                float p = __expf(e - m);
                den += p;
                pf[v] = f2bf(p);
            }
            den += __shfl_xor(den, 16, 64);
            den += __shfl_xor(den, 32, 64);
            pfr[hd][nt] = pf;
            rden[hd][nt] = 1.0f / den;
        }
    }
}

// Aggregation: out^T[d][i] = sum_j ht[d][j] * P[i][j]; head = mt >> HDSH.
template<int AGGMT, int HDSH>
__device__ __forceinline__ void agg_phase(const short* ht, const short8 (&pfr)[4][2],
                                          int c, int q, f32x4 (&acc)[AGGMT][2])
{
    const f32x4 zf = {0.f, 0.f, 0.f, 0.f};
    #pragma unroll
    for (int mt = 0; mt < AGGMT; ++mt) {
        int d = mt*16 + c;
        short4v lo = *(const short4v*)&ht[d*32 + ((2*q)   ^ (c & 7))*4];
        short4v hi = *(const short4v*)&ht[d*32 + ((2*q+1) ^ (c & 7))*4];
        short8 afr = __builtin_shufflevector(lo, hi, 0,1,2,3,4,5,6,7);
        #pragma unroll
        for (int nt = 0; nt < 2; ++nt)
            acc[mt][nt] = MFMA16(afr, pfr[mt >> HDSH][nt], zf);
    }
}

// Layer transition: xb[i][d] = agg*rden + bias[d], packed b64 writes.
__device__ __forceinline__ void trans_phase(const f32x4 (&acc)[8][2], const float (&rden)[4][2],
                                            const float* bias, short* xb, int c, int q)
{
    #pragma unroll
    for (int mt = 0; mt < 8; ++mt) {
        f32x4 bv = *(const f32x4*)&bias[mt*16 + q*4];
        #pragma unroll
        for (int nt = 0; nt < 2; ++nt) {
            float rd = rden[mt >> 1][nt];
            int ii = nt*16 + c;
            short4v o;
            #pragma unroll
            for (int r = 0; r < 4; ++r) o[r] = f2bf(fmaf(acc[mt][nt][r], rd, bv[r]));
            *(short4v*)&xb[ii*136 + mt*16 + q*4] = o;
        }
    }
}

__global__ __launch_bounds__(256, 4) void gat_mfma(
    const float* __restrict__ xs, const float* __restrict__ pe,
    const short* __restrict__ ws,
    const float* __restrict__ b1, const float* __restrict__ b2, const float* __restrict__ b3,
    const float* __restrict__ LW, const float* __restrict__ lb,
    float* __restrict__ out, int R)
{
    __shared__ short buf[4][4352];      // per-wave union: xb[32][136] <-> ht[128][32] (swz)
    __shared__ float ssx[4][264];       // [8][32] scores + M[4] @256; mcol aliases [0..23]

    int t = threadIdx.x;
    int w = t >> 6, lane = t & 63;
    int c = lane & 15, q = lane >> 4;
    int g = blockIdx.x * 4 + w;
    int b = g / R;

    short* xb = buf[w];
    short* ht = buf[w];
    float* ss = ssx[w];
    float* Msh = ss + 256;

    // ---- build x0 [32][16] bf16 (cols 16..31 zero-padded for K=32 MFMA) ----
    {
        int j = lane >> 1, half = lane & 1;
        float v[8];
        if (half == 0) {
            v[0] = xs[g*32 + j];
            #pragma unroll
            for (int kk = 0; kk < 7; ++kk) v[1+kk] = pe[b*480 + j*15 + kk];
        } else {
            #pragma unroll
            for (int kk = 0; kk < 8; ++kk) v[kk] = pe[b*480 + j*15 + 7 + kk];
        }
        short8 px;
        #pragma unroll
        for (int kk = 0; kk < 8; ++kk) px[kk] = f2bf(v[kk]);
        *(short8*)&xb[j*136 + half*8] = px;
        *(short8*)&xb[j*136 + 16 + half*8] = (short8){0,0,0,0,0,0,0,0};
    }

    const short* wt1 = ws;
    const short* wt2 = ws + 4608;
    const short* wt3 = ws + 23040;

    // ================= layer 1 (K=16 padded to 32, N = 128 h + 8 score) ===========
    {
        f32x4 acc[2][9];
        gemm_phase<1,9>(xb, wt1, c, q, acc);
        write_ht_scores<8,9>(acc, ht, ss, c, q);
        max_phase(ss, Msh, lane);
        short8 pfr[4][2]; float rden[4][2];
        frag_phase(ss, Msh, c, q, pfr, rden);
        f32x4 agg[8][2];
        agg_phase<8,1>(ht, pfr, c, q, agg);
        trans_phase(agg, rden, b1, xb, c, q);
    }
    // ================= layer 2 (K=128) ============================================
    {
        f32x4 acc[2][9];
        gemm_phase<4,9>(xb, wt2, c, q, acc);
        write_ht_scores<8,9>(acc, ht, ss, c, q);
        max_phase(ss, Msh, lane);
        short8 pfr[4][2]; float rden[4][2];
        frag_phase(ss, Msh, c, q, pfr, rden);
        f32x4 agg[8][2];
        agg_phase<8,1>(ht, pfr, c, q, agg);
        trans_phase(agg, rden, b2, xb, c, q);
    }
    // ================= layer 3 (out dim 24, head-padded to 4x16) ==================
    {
        f32x4 acc[2][5];
        gemm_phase<4,5>(xb, wt3, c, q, acc);
        write_ht_scores<4,5>(acc, ht, ss, c, q);
        max_phase(ss, Msh, lane);
        short8 pfr[4][2]; float rden[4][2];
        frag_phase(ss, Msh, c, q, pfr, rden);
        f32x4 agg[4][2];
        agg_phase<4,0>(ht, pfr, c, q, agg);

        // normalize + mean over nodes i: in-lane nt-fma, then butterfly over c bits
        float red[4][4];
        #pragma unroll
        for (int mt = 0; mt < 4; ++mt)
          #pragma unroll
          for (int r = 0; r < 4; ++r)
            red[mt][r] = fmaf(agg[mt][0][r], rden[mt][0], agg[mt][1][r] * rden[mt][1]);
        #pragma unroll
        for (int m = 1; m < 16; m <<= 1)
          #pragma unroll
          for (int mt = 0; mt < 4; ++mt)
            #pragma unroll
            for (int r = 0; r < 4; ++r)
              red[mt][r] += __shfl_xor(red[mt][r], m, 64);
        if (c == 0) {     // mcol aliases ss[0..23] (scores dead now)
          #pragma unroll
          for (int mt = 0; mt < 4; ++mt)
            #pragma unroll
            for (int r = 0; r < 4; ++r) {
              int dl = q*4 + r;                       // real only for dl < 6
              if (dl < 6)
                ss[mt*6 + dl] = red[mt][r] * (1.f/32.f) + b3[mt*6 + dl];
            }
        }
    }
    // ---- epilogue: out[g] = mcol @ lin_w + lin_b (f32) ----
    {
        float o = lb[lane];
        #pragma unroll
        for (int cc = 0; cc < 24; ++cc)
            o = fmaf(ss[cc], LW[cc*64 + lane], o);
        out[g*64 + lane] = o;
    }
}

extern "C" void kernel_launch(void* const* d_in, const int* in_sizes, int n_in,
                              void* d_out, int out_size, void* d_ws, size_t ws_size,
                              hipStream_t stream) {
    const float* xs  = (const float*)d_in[0];
    const float* pe  = (const float*)d_in[1];
    const float* W1  = (const float*)d_in[2];
    const float* as1 = (const float*)d_in[3];
    const float* ad1 = (const float*)d_in[4];
    const float* b1  = (const float*)d_in[5];
    const float* W2  = (const float*)d_in[6];
    const float* as2 = (const float*)d_in[7];
    const float* ad2 = (const float*)d_in[8];
    const float* b2  = (const float*)d_in[9];
    const float* W3  = (const float*)d_in[10];
    const float* as3 = (const float*)d_in[11];
    const float* ad3 = (const float*)d_in[12];
    const float* b3  = (const float*)d_in[13];
    const float* LW  = (const float*)d_in[14];
    const float* lb  = (const float*)d_in[15];
    float* o = (float*)d_out;
    short* ws = (short*)d_ws;

    int G = in_sizes[0] / 32;       // B*R graphs (16384)
    int B = in_sizes[1] / 480;      // pos_enc = B*32*15
    int R = G / B;

    build_wt<<<dim3(130), dim3(256), 0, stream>>>(W1, as1, ad1, W2, as2, ad2,
                                                  W3, as3, ad3, ws);
    gat_mfma<<<dim3(G/4), dim3(256), 0, stream>>>(xs, pe, ws, b1, b2, b3, LW, lb, o, R);
}

// Round 6
// 111.119 us; speedup vs baseline: 21.3117x; 1.2426x over previous
//
#include <hip/hip_runtime.h>
#include <hip/hip_bf16.h>

// GNN2: 3-layer GAT over 16384 independent 32-node cliques.
// One WAVE per graph (4 graphs / 256-thread block), zero barriers.
// GEMMs + attention-aggregation on mfma_f32_16x16x32_bf16; scores fused into
// the GEMM via pre-multiplied Wa = W @ [a_src|a_dst] columns. f32 accumulate.
// Per-nt GEMM interleave + per-head fused frag/agg -> peak live regs ~100 (no
// spill at 4 blk/CU). ht swizzle s(c)=(c>>1)&7 -> bank-uniform b64 r/w.
// Layer 3: packed 24+8 GEMM (NT=2), P-as-A aggregation, in-register node-mean.

typedef __attribute__((ext_vector_type(8))) short short8;
typedef __attribute__((ext_vector_type(4))) short short4v;
typedef __attribute__((ext_vector_type(4))) float f32x4;

#define MFMA16(a,b,c) __builtin_amdgcn_mfma_f32_16x16x32_bf16(a,b,c,0,0,0)

__device__ __forceinline__ short f2bf(float f) {
    __hip_bfloat16 h = __float2bfloat16(f);
    return *reinterpret_cast<short*>(&h);
}

// ---------------- pre-kernel: tiled transposed bf16 weights in ws ----------------
// Tile layout per layer: [nt][kc][16][32] bf16 — B-frag loads 1KB contiguous/wave.
//  wt1 [0,4608):       NT=9, KC=1. n=nt*16+c: n<128 -> W1[k][n] (k<16 else 0);
//                      n in 128..135 -> Wa1 col (n-128); else 0
//  wt2 [4608,23040):   NT=9, KC=4. same scheme for W2/Wa2
//  wt3 [23040,27136):  NT=2, KC=4. n<24 -> W3[k][n] (packed hd*6+dl);
//                      n in 24..31 -> Wa3 col (n-24)
__global__ __launch_bounds__(256) void build_wt(
    const float* __restrict__ W1, const float* __restrict__ as1, const float* __restrict__ ad1,
    const float* __restrict__ W2, const float* __restrict__ as2, const float* __restrict__ ad2,
    const float* __restrict__ W3, const float* __restrict__ as3, const float* __restrict__ ad3,
    short* __restrict__ ws)
{
    int i = blockIdx.x * 256 + threadIdx.x;
    float val = 0.f;
    if (i < 4608) {                       // layer 1 (KC=1 -> [n][k])
        int n = i >> 5, k = i & 31;
        if (k < 16) {
            if (n < 128) val = W1[k*128 + n];
            else if (n < 136) {
                int cc = n - 128; const float* a = (cc < 4) ? as1 : ad1;
                for (int dl = 0; dl < 32; ++dl)
                    val += W1[k*128 + (cc&3)*32 + dl] * a[(cc&3)*32 + dl];
            }
        }
        ws[i] = f2bf(val);
    } else if (i < 23040) {               // layer 2
        int j = i - 4608;
        int kq = j & 31, c = (j >> 5) & 15, kc = (j >> 9) & 3, nt = j >> 11;
        int n = nt*16 + c, k = kc*32 + kq;
        if (n < 128) val = W2[k*128 + n];
        else if (n < 136) {
            int cc = n - 128; const float* a = (cc < 4) ? as2 : ad2;
            for (int dl = 0; dl < 32; ++dl)
                val += W2[k*128 + (cc&3)*32 + dl] * a[(cc&3)*32 + dl];
        }
        ws[i] = f2bf(val);
    } else {                              // layer 3 (packed 24 + 8 score)
        int j = i - 23040;
        int kq = j & 31, c = (j >> 5) & 15, kc = (j >> 9) & 3, nt = j >> 11;
        int n = nt*16 + c, k = kc*32 + kq;
        if (n < 24) val = W3[k*24 + n];
        else {
            int cc = n - 24; const float* a = (cc < 4) ? as3 : ad3;
            for (int dl = 0; dl < 6; ++dl)
                val += W3[k*24 + (cc&3)*6 + dl] * a[(cc&3)*6 + dl];
        }
        ws[i] = f2bf(val);
    }
}

// ---------------- main-kernel phases ----------------
// Fragment layout (gfx950 16x16x32 bf16): A: row=lane&15, k=8*(lane>>4)+v;
// B: col=lane&15, k=8*(lane>>4)+v; D: col=lane&15, row=4*(lane>>4)+r. [m89/m93]
// ht swizzle: j-granule kj of row d stored at physical granule kj ^ ((d&15)>>1).

// GEMM + ht/score write, per-nt interleaved (A-frags preloaded; xb dead after).
template<int KC, int NT, int NTH>
__device__ __forceinline__ void gemm_ht(short* buf, const short* __restrict__ wt,
                                        float* ss, int c, int q)
{
    const f32x4 zf = {0.f, 0.f, 0.f, 0.f};
    short8 afr[2][KC];
    #pragma unroll
    for (int mt = 0; mt < 2; ++mt)
      #pragma unroll
      for (int kc = 0; kc < KC; ++kc)
        afr[mt][kc] = *(const short8*)&buf[(mt*16 + c)*136 + kc*32 + q*8];
    int sw = c >> 1;
    #pragma unroll
    for (int nt = 0; nt < NT; ++nt) {
        f32x4 a0 = zf, a1 = zf;
        #pragma unroll
        for (int kc = 0; kc < KC; ++kc) {
            short8 bfr = *(const short8*)&wt[((nt*KC + kc)*16 + c)*32 + q*8];
            a0 = MFMA16(afr[0][kc], bfr, a0);
            a1 = MFMA16(afr[1][kc], bfr, a1);
        }
        if (nt < NTH) {
            int d = nt*16 + c;
            short4v h0, h1;
            #pragma unroll
            for (int r = 0; r < 4; ++r) { h0[r] = f2bf(a0[r]); h1[r] = f2bf(a1[r]); }
            *(short4v*)&buf[d*32 + (q ^ sw)*4]       = h0;
            *(short4v*)&buf[d*32 + ((4+q) ^ sw)*4]   = h1;
        } else if (c < 8) {   // score tile: rows c<4 = s_src head c, c>=4 = s_dst
            *(f32x4*)&ss[c*32 + q*4]      = a0;
            *(f32x4*)&ss[c*32 + 16 + q*4] = a1;
        }
    }
}

// Per-head source max: M[hd] = max_j s_src[hd][j] (exact via monotone lrelu).
__device__ __forceinline__ void max_phase(const float* ss, float* Msh, int lane)
{
    int hd2 = lane >> 4, jj = lane & 15;
    float v = fmaxf(ss[hd2*32 + jj], ss[hd2*32 + 16 + jj]);
    #pragma unroll
    for (int m = 1; m < 16; m <<= 1)
        v = fmaxf(v, __shfl_xor(v, m, 64));
    if (jj == 0) Msh[hd2] = v;
}

// Fused frag+agg (layers 1-2): per head build P-frags, then 2 MFMAs per M-tile.
__device__ __forceinline__ void agg12(const short* buf, const float* ss, const float* Msh,
                                      int c, int q, f32x4 (&acc)[8][2], float (&rden)[4][2])
{
    const f32x4 zf = {0.f, 0.f, 0.f, 0.f};
    int sw = c >> 1;
    #pragma unroll
    for (int hd = 0; hd < 4; ++hd) {
        float Mh = Msh[hd];
        f32x4 v0 = *(const f32x4*)&ss[hd*32 + q*8];
        f32x4 v1 = *(const f32x4*)&ss[hd*32 + q*8 + 4];
        short8 pf[2];
        #pragma unroll
        for (int it = 0; it < 2; ++it) {
            float sd = ss[(4+hd)*32 + it*16 + c];
            float m = sd + Mh; m = fmaxf(m, 0.2f*m);
            float den = 0.f; short8 t;
            #pragma unroll
            for (int v = 0; v < 8; ++v) {
                float sj = (v < 4) ? v0[v] : v1[v-4];
                float e = sd + sj; e = fmaxf(e, 0.2f*e);
                float p = __expf(e - m);
                den += p;
                t[v] = f2bf(p);
            }
            den += __shfl_xor(den, 16, 64);
            den += __shfl_xor(den, 32, 64);
            pf[it] = t; rden[hd][it] = 1.0f / den;
        }
        #pragma unroll
        for (int m2 = 0; m2 < 2; ++m2) {
            int mt = hd*2 + m2, d = mt*16 + c;
            short4v lo = *(const short4v*)&buf[d*32 + ((2*q)   ^ sw)*4];
            short4v hi = *(const short4v*)&buf[d*32 + ((2*q+1) ^ sw)*4];
            short8 af = __builtin_shufflevector(lo, hi, 0,1,2,3,4,5,6,7);
            acc[mt][0] = MFMA16(af, pf[0], zf);
            acc[mt][1] = MFMA16(af, pf[1], zf);
        }
    }
}

// Layer transition: xb[i][d] = agg*rden + bias[d], packed b64 writes.
__device__ __forceinline__ void trans_phase(const f32x4 (&acc)[8][2], const float (&rden)[4][2],
                                            const float* bias, short* xb, int c, int q)
{
    #pragma unroll
    for (int mt = 0; mt < 8; ++mt) {
        f32x4 bv = *(const f32x4*)&bias[mt*16 + q*4];
        #pragma unroll
        for (int nt = 0; nt < 2; ++nt) {
            float rd = rden[mt >> 1][nt];
            int ii = nt*16 + c;
            short4v o;
            #pragma unroll
            for (int r = 0; r < 4; ++r) o[r] = f2bf(fmaf(acc[mt][nt][r], rd, bv[r]));
            *(short4v*)&xb[ii*136 + mt*16 + q*4] = o;
        }
    }
}

// Layer-3 GEMM: packed cols [24 h | 8 score], NT=2; ht rows head-padded hd*16+dl,
// pad rows zero-filled (after A-frag preload frees the xb region).
__device__ __forceinline__ void gemm3_ht(short* buf, const short* __restrict__ wt,
                                         float* ss, int c, int q, int lane)
{
    const f32x4 zf = {0.f, 0.f, 0.f, 0.f};
    short8 afr[2][4];
    #pragma unroll
    for (int mt = 0; mt < 2; ++mt)
      #pragma unroll
      for (int kc = 0; kc < 4; ++kc)
        afr[mt][kc] = *(const short8*)&buf[(mt*16 + c)*136 + kc*32 + q*8];
    {   // zero-fill pad rows hd*16+dl, dl in 6..15 (40 rows x 8 granules = 320 b64)
        const short4v z4 = {0, 0, 0, 0};
        #pragma unroll
        for (int k = 0; k < 5; ++k) {
            int flat = lane + k*64;
            int z = flat >> 3, gg = flat & 7;
            int row = (z/10)*16 + 6 + (z%10);
            *(short4v*)&buf[row*32 + gg*4] = z4;
        }
    }
    #pragma unroll
    for (int nt = 0; nt < 2; ++nt) {
        f32x4 a0 = zf, a1 = zf;
        #pragma unroll
        for (int kc = 0; kc < 4; ++kc) {
            short8 bfr = *(const short8*)&wt[((nt*4 + kc)*16 + c)*32 + q*8];
            a0 = MFMA16(afr[0][kc], bfr, a0);
            a1 = MFMA16(afr[1][kc], bfr, a1);
        }
        int p = nt*16 + c;
        if (p < 24) {
            int row = (p/6)*16 + (p%6);
            int sw3 = (row & 15) >> 1;
            short4v h0, h1;
            #pragma unroll
            for (int r = 0; r < 4; ++r) { h0[r] = f2bf(a0[r]); h1[r] = f2bf(a1[r]); }
            *(short4v*)&buf[row*32 + (q ^ sw3)*4]     = h0;
            *(short4v*)&buf[row*32 + ((4+q) ^ sw3)*4] = h1;
        } else if (c >= 8) {   // score cols
            *(f32x4*)&ss[(c-8)*32 + q*4]      = a0;
            *(f32x4*)&ss[(c-8)*32 + 16 + q*4] = a1;
        }
    }
}

// Layer-3 aggregation with P as A-operand + in-register node-mean -> mcol[24].
__device__ __forceinline__ void agg3_mean(const short* buf, const float* ss, const float* Msh,
                                          const float* b3, float* mcol, int c, int q)
{
    const f32x4 zf = {0.f, 0.f, 0.f, 0.f};
    int sw = c >> 1;
    float vout[4];
    #pragma unroll
    for (int hd = 0; hd < 4; ++hd) {
        float Mh = Msh[hd];
        f32x4 v0 = *(const f32x4*)&ss[hd*32 + q*8];
        f32x4 v1 = *(const f32x4*)&ss[hd*32 + q*8 + 4];
        short8 pf[2];
        #pragma unroll
        for (int it = 0; it < 2; ++it) {
            float sd = ss[(4+hd)*32 + it*16 + c];
            float m = sd + Mh; m = fmaxf(m, 0.2f*m);
            float pv[8]; float den = 0.f;
            #pragma unroll
            for (int v = 0; v < 8; ++v) {
                float sj = (v < 4) ? v0[v] : v1[v-4];
                float e = sd + sj; e = fmaxf(e, 0.2f*e);
                pv[v] = __expf(e - m);
                den += pv[v];
            }
            den += __shfl_xor(den, 16, 64);
            den += __shfl_xor(den, 32, 64);
            float rd = 1.0f / den;
            short8 t;
            #pragma unroll
            for (int v = 0; v < 8; ++v) t[v] = f2bf(pv[v] * rd);
            pf[it] = t;
        }
        int d = hd*16 + c;
        short4v lo = *(const short4v*)&buf[d*32 + ((2*q)   ^ sw)*4];
        short4v hi = *(const short4v*)&buf[d*32 + ((2*q+1) ^ sw)*4];
        short8 bf_ = __builtin_shufflevector(lo, hi, 0,1,2,3,4,5,6,7);
        f32x4 o0 = MFMA16(pf[0], bf_, zf);   // D: row=i(4q+r), col=c within head hd
        f32x4 o1 = MFMA16(pf[1], bf_, zf);
        float s = (o0[0]+o0[1]) + (o0[2]+o0[3]) + (o1[0]+o1[1]) + (o1[2]+o1[3]);
        s += __shfl_xor(s, 16, 64);
        s += __shfl_xor(s, 32, 64);
        vout[hd] = s;
    }
    if (q == 0 && c < 6) {
        #pragma unroll
        for (int hd = 0; hd < 4; ++hd)
            mcol[hd*6 + c] = vout[hd] * (1.f/32.f) + b3[hd*6 + c];
    }
}

__global__ __launch_bounds__(256, 4) void gat_mfma(
    const float* __restrict__ xs, const float* __restrict__ pe,
    const short* __restrict__ ws,
    const float* __restrict__ b1, const float* __restrict__ b2, const float* __restrict__ b3,
    const float* __restrict__ LW, const float* __restrict__ lb,
    float* __restrict__ out, int R)
{
    __shared__ short buf[4][4352];      // per-wave union: xb[32][136] <-> ht[*][32] (swz)
    __shared__ float ssx[4][264];       // [8][32] scores + M[4] @256; mcol aliases [0..23]

    int t = threadIdx.x;
    int w = t >> 6, lane = t & 63;
    int c = lane & 15, q = lane >> 4;
    int g = blockIdx.x * 4 + w;
    int b = g / R;

    short* xb = buf[w];
    float* ss = ssx[w];
    float* Msh = ss + 256;

    // ---- build x0 [32][16] bf16 (cols 16..31 zero-padded for K=32 MFMA) ----
    {
        int j = lane >> 1, half = lane & 1;
        float v[8];
        if (half == 0) {
            v[0] = xs[g*32 + j];
            #pragma unroll
            for (int kk = 0; kk < 7; ++kk) v[1+kk] = pe[b*480 + j*15 + kk];
        } else {
            #pragma unroll
            for (int kk = 0; kk < 8; ++kk) v[kk] = pe[b*480 + j*15 + 7 + kk];
        }
        short8 px;
        #pragma unroll
        for (int kk = 0; kk < 8; ++kk) px[kk] = f2bf(v[kk]);
        *(short8*)&xb[j*136 + half*8] = px;
        *(short8*)&xb[j*136 + 16 + half*8] = (short8){0,0,0,0,0,0,0,0};
    }

    const short* wt1 = ws;
    const short* wt2 = ws + 4608;
    const short* wt3 = ws + 23040;

    // ================= layer 1 (K=16 padded to 32) =================
    {
        gemm_ht<1,9,8>(xb, wt1, ss, c, q);
        max_phase(ss, Msh, lane);
        f32x4 acc[8][2]; float rden[4][2];
        agg12(xb, ss, Msh, c, q, acc, rden);
        trans_phase(acc, rden, b1, xb, c, q);
    }
    // ================= layer 2 (K=128) =============================
    {
        gemm_ht<4,9,8>(xb, wt2, ss, c, q);
        max_phase(ss, Msh, lane);
        f32x4 acc[8][2]; float rden[4][2];
        agg12(xb, ss, Msh, c, q, acc, rden);
        trans_phase(acc, rden, b2, xb, c, q);
    }
    // ================= layer 3 (packed 24+8, P-as-A agg, mean) =====
    {
        gemm3_ht(xb, wt3, ss, c, q, lane);
        max_phase(ss, Msh, lane);
        agg3_mean(xb, ss, Msh, b3, ss, c, q);   // mcol aliases ss[0..23]
    }
    // ---- epilogue: out[g] = mcol @ lin_w + lin_b (f32) ----
    {
        float o = lb[lane];
        #pragma unroll
        for (int cc = 0; cc < 24; ++cc)
            o = fmaf(ss[cc], LW[cc*64 + lane], o);
        out[g*64 + lane] = o;
    }
}

extern "C" void kernel_launch(void* const* d_in, const int* in_sizes, int n_in,
                              void* d_out, int out_size, void* d_ws, size_t ws_size,
                              hipStream_t stream) {
    const float* xs  = (const float*)d_in[0];
    const float* pe  = (const float*)d_in[1];
    const float* W1  = (const float*)d_in[2];
    const float* as1 = (const float*)d_in[3];
    const float* ad1 = (const float*)d_in[4];
    const float* b1  = (const float*)d_in[5];
    const float* W2  = (const float*)d_in[6];
    const float* as2 = (const float*)d_in[7];
    const float* ad2 = (const float*)d_in[8];
    const float* b2  = (const float*)d_in[9];
    const float* W3  = (const float*)d_in[10];
    const float* as3 = (const float*)d_in[11];
    const float* ad3 = (const float*)d_in[12];
    const float* b3  = (const float*)d_in[13];
    const float* LW  = (const float*)d_in[14];
    const float* lb  = (const float*)d_in[15];
    float* o = (float*)d_out;
    short* ws = (short*)d_ws;

    int G = in_sizes[0] / 32;       // B*R graphs (16384)
    int B = in_sizes[1] / 480;      // pos_enc = B*32*15
    int R = G / B;

    build_wt<<<dim3(106), dim3(256), 0, stream>>>(W1, as1, ad1, W2, as2, ad2,
                                                  W3, as3, ad3, ws);
    gat_mfma<<<dim3(G/4), dim3(256), 0, stream>>>(xs, pe, ws, b1, b2, b3, LW, lb, o, R);
}

// Round 7
// 96.445 us; speedup vs baseline: 24.5542x; 1.1521x over previous
//
#include <hip/hip_runtime.h>
#include <hip/hip_bf16.h>

// GNN2: 3-layer GAT over 16384 independent 32-node cliques.
// One WAVE per graph (4 graphs / 256-thread block), zero barriers.
// GEMMs + attention-aggregation on mfma_f32_16x16x32_bf16; scores fused into
// the GEMM via pre-multiplied Wa = W @ [a_src|a_dst] columns, PRE-SCALED by
// log2(e) so softmax runs in the exp2 domain with NO max-subtraction
// (shift-invariant, scores O(1)). ht swizzle s(c)=(c>>1) -> bank-uniform r/w.
// Layer 3: packed 24+8 GEMM (NT=2), P-as-A aggregation, in-register node-mean.

typedef __attribute__((ext_vector_type(8))) short short8;
typedef __attribute__((ext_vector_type(4))) short short4v;
typedef __attribute__((ext_vector_type(4))) float f32x4;

#define MFMA16(a,b,c) __builtin_amdgcn_mfma_f32_16x16x32_bf16(a,b,c,0,0,0)
#define L2E 1.4426950408889634f

__device__ __forceinline__ short f2bf(float f) {
    __hip_bfloat16 h = __float2bfloat16(f);
    return *reinterpret_cast<short*>(&h);
}
__device__ __forceinline__ float fexp2(float x) { return __builtin_amdgcn_exp2f(x); }

// ---------------- pre-kernel: tiled transposed bf16 weights in ws ----------------
// Tile layout per layer: [nt][kc][16][32] bf16 — B-frag loads 1KB contiguous/wave.
//  wt1 [0,4608):       NT=9, KC=1. n=nt*16+c: n<128 -> W1[k][n] (k<16 else 0);
//                      n in 128..135 -> L2E * Wa1 col (n-128); else 0
//  wt2 [4608,23040):   NT=9, KC=4. same scheme for W2/Wa2
//  wt3 [23040,27136):  NT=2, KC=4. n<24 -> W3[k][n] (packed hd*6+dl);
//                      n in 24..31 -> L2E * Wa3 col (n-24)
__global__ __launch_bounds__(256) void build_wt(
    const float* __restrict__ W1, const float* __restrict__ as1, const float* __restrict__ ad1,
    const float* __restrict__ W2, const float* __restrict__ as2, const float* __restrict__ ad2,
    const float* __restrict__ W3, const float* __restrict__ as3, const float* __restrict__ ad3,
    short* __restrict__ ws)
{
    int i = blockIdx.x * 256 + threadIdx.x;
    float val = 0.f;
    if (i < 4608) {                       // layer 1 (KC=1 -> [n][k])
        int n = i >> 5, k = i & 31;
        if (k < 16) {
            if (n < 128) val = W1[k*128 + n];
            else if (n < 136) {
                int cc = n - 128; const float* a = (cc < 4) ? as1 : ad1;
                for (int dl = 0; dl < 32; ++dl)
                    val += W1[k*128 + (cc&3)*32 + dl] * a[(cc&3)*32 + dl];
                val *= L2E;
            }
        }
        ws[i] = f2bf(val);
    } else if (i < 23040) {               // layer 2
        int j = i - 4608;
        int kq = j & 31, c = (j >> 5) & 15, kc = (j >> 9) & 3, nt = j >> 11;
        int n = nt*16 + c, k = kc*32 + kq;
        if (n < 128) val = W2[k*128 + n];
        else if (n < 136) {
            int cc = n - 128; const float* a = (cc < 4) ? as2 : ad2;
            for (int dl = 0; dl < 32; ++dl)
                val += W2[k*128 + (cc&3)*32 + dl] * a[(cc&3)*32 + dl];
            val *= L2E;
        }
        ws[i] = f2bf(val);
    } else {                              // layer 3 (packed 24 + 8 score)
        int j = i - 23040;
        int kq = j & 31, c = (j >> 5) & 15, kc = (j >> 9) & 3, nt = j >> 11;
        int n = nt*16 + c, k = kc*32 + kq;
        if (n < 24) val = W3[k*24 + n];
        else {
            int cc = n - 24; const float* a = (cc < 4) ? as3 : ad3;
            for (int dl = 0; dl < 6; ++dl)
                val += W3[k*24 + (cc&3)*6 + dl] * a[(cc&3)*6 + dl];
            val *= L2E;
        }
        ws[i] = f2bf(val);
    }
}

// ---------------- main-kernel phases ----------------
// Fragment layout (gfx950 16x16x32 bf16): A: row=lane&15, k=8*(lane>>4)+v;
// B: col=lane&15, k=8*(lane>>4)+v; D: col=lane&15, row=4*(lane>>4)+r. [m89/m93]
// ht swizzle: j-granule kj of row d stored at physical granule kj ^ ((d&15)>>1).

// GEMM + ht/score write, per-nt interleaved (A-frags preloaded; xb dead after).
template<int KC, int NT, int NTH>
__device__ __forceinline__ void gemm_ht(short* buf, const short* __restrict__ wt,
                                        float* ss, int c, int q)
{
    const f32x4 zf = {0.f, 0.f, 0.f, 0.f};
    short8 afr[2][KC];
    #pragma unroll
    for (int mt = 0; mt < 2; ++mt)
      #pragma unroll
      for (int kc = 0; kc < KC; ++kc)
        afr[mt][kc] = *(const short8*)&buf[(mt*16 + c)*136 + kc*32 + q*8];
    int sw = c >> 1;
    #pragma unroll
    for (int nt = 0; nt < NT; ++nt) {
        f32x4 a0 = zf, a1 = zf;
        #pragma unroll
        for (int kc = 0; kc < KC; ++kc) {
            short8 bfr = *(const short8*)&wt[((nt*KC + kc)*16 + c)*32 + q*8];
            a0 = MFMA16(afr[0][kc], bfr, a0);
            a1 = MFMA16(afr[1][kc], bfr, a1);
        }
        if (nt < NTH) {
            int d = nt*16 + c;
            short4v h0, h1;
            #pragma unroll
            for (int r = 0; r < 4; ++r) { h0[r] = f2bf(a0[r]); h1[r] = f2bf(a1[r]); }
            *(short4v*)&buf[d*32 + (q ^ sw)*4]       = h0;
            *(short4v*)&buf[d*32 + ((4+q) ^ sw)*4]   = h1;
        } else if (c < 8) {   // score tile: rows c<4 = s_src head c, c>=4 = s_dst
            *(f32x4*)&ss[c*32 + q*4]      = a0;
            *(f32x4*)&ss[c*32 + 16 + q*4] = a1;
        }
    }
}

// Fused frag+agg (layers 1-2): per head build P-frags (exp2 domain, no max-sub),
// then 2 MFMAs per M-tile.
__device__ __forceinline__ void agg12(const short* buf, const float* ss,
                                      int c, int q, f32x4 (&acc)[8][2], float (&rden)[4][2])
{
    const f32x4 zf = {0.f, 0.f, 0.f, 0.f};
    int sw = c >> 1;
    #pragma unroll
    for (int hd = 0; hd < 4; ++hd) {
        f32x4 v0 = *(const f32x4*)&ss[hd*32 + q*8];
        f32x4 v1 = *(const f32x4*)&ss[hd*32 + q*8 + 4];
        short8 pf[2];
        #pragma unroll
        for (int it = 0; it < 2; ++it) {
            float sd = ss[(4+hd)*32 + it*16 + c];
            float den = 0.f; short8 t;
            #pragma unroll
            for (int v = 0; v < 8; ++v) {
                float sj = (v < 4) ? v0[v] : v1[v-4];
                float e = sd + sj; e = fmaxf(e, 0.2f*e);   // lrelu, log2 domain
                float p = fexp2(e);
                den += p;
                t[v] = f2bf(p);
            }
            den += __shfl_xor(den, 16, 64);
            den += __shfl_xor(den, 32, 64);
            pf[it] = t; rden[hd][it] = 1.0f / den;
        }
        #pragma unroll
        for (int m2 = 0; m2 < 2; ++m2) {
            int mt = hd*2 + m2, d = mt*16 + c;
            short4v lo = *(const short4v*)&buf[d*32 + ((2*q)   ^ sw)*4];
            short4v hi = *(const short4v*)&buf[d*32 + ((2*q+1) ^ sw)*4];
            short8 af = __builtin_shufflevector(lo, hi, 0,1,2,3,4,5,6,7);
            acc[mt][0] = MFMA16(af, pf[0], zf);
            acc[mt][1] = MFMA16(af, pf[1], zf);
        }
    }
}

// Layer transition: xb[i][d] = agg*rden + bias[d], packed b64 writes.
__device__ __forceinline__ void trans_phase(const f32x4 (&acc)[8][2], const float (&rden)[4][2],
                                            const float* bias, short* xb, int c, int q)
{
    #pragma unroll
    for (int mt = 0; mt < 8; ++mt) {
        f32x4 bv = *(const f32x4*)&bias[mt*16 + q*4];
        #pragma unroll
        for (int nt = 0; nt < 2; ++nt) {
            float rd = rden[mt >> 1][nt];
            int ii = nt*16 + c;
            short4v o;
            #pragma unroll
            for (int r = 0; r < 4; ++r) o[r] = f2bf(fmaf(acc[mt][nt][r], rd, bv[r]));
            *(short4v*)&xb[ii*136 + mt*16 + q*4] = o;
        }
    }
}

// Layer-3 GEMM: packed cols [24 h | 8 score], NT=2; ht rows head-padded hd*16+dl,
// pad rows zero-filled (after A-frag preload frees the xb region).
__device__ __forceinline__ void gemm3_ht(short* buf, const short* __restrict__ wt,
                                         float* ss, int c, int q, int lane)
{
    const f32x4 zf = {0.f, 0.f, 0.f, 0.f};
    short8 afr[2][4];
    #pragma unroll
    for (int mt = 0; mt < 2; ++mt)
      #pragma unroll
      for (int kc = 0; kc < 4; ++kc)
        afr[mt][kc] = *(const short8*)&buf[(mt*16 + c)*136 + kc*32 + q*8];
    {   // zero-fill pad rows hd*16+dl, dl in 6..15 (40 rows x 8 granules = 320 b64)
        const short4v z4 = {0, 0, 0, 0};
        #pragma unroll
        for (int k = 0; k < 5; ++k) {
            int flat = lane + k*64;
            int z = flat >> 3, gg = flat & 7;
            int row = (z/10)*16 + 6 + (z%10);
            *(short4v*)&buf[row*32 + gg*4] = z4;
        }
    }
    #pragma unroll
    for (int nt = 0; nt < 2; ++nt) {
        f32x4 a0 = zf, a1 = zf;
        #pragma unroll
        for (int kc = 0; kc < 4; ++kc) {
            short8 bfr = *(const short8*)&wt[((nt*4 + kc)*16 + c)*32 + q*8];
            a0 = MFMA16(afr[0][kc], bfr, a0);
            a1 = MFMA16(afr[1][kc], bfr, a1);
        }
        int p = nt*16 + c;
        if (p < 24) {
            int row = (p/6)*16 + (p%6);
            int sw3 = (row & 15) >> 1;
            short4v h0, h1;
            #pragma unroll
            for (int r = 0; r < 4; ++r) { h0[r] = f2bf(a0[r]); h1[r] = f2bf(a1[r]); }
            *(short4v*)&buf[row*32 + (q ^ sw3)*4]     = h0;
            *(short4v*)&buf[row*32 + ((4+q) ^ sw3)*4] = h1;
        } else if (c >= 8) {   // score cols
            *(f32x4*)&ss[(c-8)*32 + q*4]      = a0;
            *(f32x4*)&ss[(c-8)*32 + 16 + q*4] = a1;
        }
    }
}

// Layer-3 aggregation with P as A-operand + in-register node-mean -> mcol[24].
__device__ __forceinline__ void agg3_mean(const short* buf, const float* ss,
                                          const float* b3, float* mcol, int c, int q)
{
    const f32x4 zf = {0.f, 0.f, 0.f, 0.f};
    int sw = c >> 1;
    float vout[4];
    #pragma unroll
    for (int hd = 0; hd < 4; ++hd) {
        f32x4 v0 = *(const f32x4*)&ss[hd*32 + q*8];
        f32x4 v1 = *(const f32x4*)&ss[hd*32 + q*8 + 4];
        short8 pf[2];
        #pragma unroll
        for (int it = 0; it < 2; ++it) {
            float sd = ss[(4+hd)*32 + it*16 + c];
            float pv[8]; float den = 0.f;
            #pragma unroll
            for (int v = 0; v < 8; ++v) {
                float sj = (v < 4) ? v0[v] : v1[v-4];
                float e = sd + sj; e = fmaxf(e, 0.2f*e);
                pv[v] = fexp2(e);
                den += pv[v];
            }
            den += __shfl_xor(den, 16, 64);
            den += __shfl_xor(den, 32, 64);
            float rd = 1.0f / den;
            short8 t;
            #pragma unroll
            for (int v = 0; v < 8; ++v) t[v] = f2bf(pv[v] * rd);
            pf[it] = t;
        }
        int d = hd*16 + c;
        short4v lo = *(const short4v*)&buf[d*32 + ((2*q)   ^ sw)*4];
        short4v hi = *(const short4v*)&buf[d*32 + ((2*q+1) ^ sw)*4];
        short8 bf_ = __builtin_shufflevector(lo, hi, 0,1,2,3,4,5,6,7);
        f32x4 o0 = MFMA16(pf[0], bf_, zf);   // D: row=i(4q+r), col=c within head hd
        f32x4 o1 = MFMA16(pf[1], bf_, zf);
        float s = (o0[0]+o0[1]) + (o0[2]+o0[3]) + (o1[0]+o1[1]) + (o1[2]+o1[3]);
        s += __shfl_xor(s, 16, 64);
        s += __shfl_xor(s, 32, 64);
        vout[hd] = s;
    }
    if (q == 0 && c < 6) {
        #pragma unroll
        for (int hd = 0; hd < 4; ++hd)
            mcol[hd*6 + c] = vout[hd] * (1.f/32.f) + b3[hd*6 + c];
    }
}

__global__ __launch_bounds__(256, 4) void gat_mfma(
    const float* __restrict__ xs, const float* __restrict__ pe,
    const short* __restrict__ ws,
    const float* __restrict__ b1, const float* __restrict__ b2, const float* __restrict__ b3,
    const float* __restrict__ LW, const float* __restrict__ lb,
    float* __restrict__ out, int R)
{
    __shared__ short buf[4][4352];      // per-wave union: xb[32][136] <-> ht[*][32] (swz)
    __shared__ float ssx[4][256];       // [8][32] scores; mcol aliases [0..23]

    int t = threadIdx.x;
    int w = t >> 6, lane = t & 63;
    int c = lane & 15, q = lane >> 4;
    int g = blockIdx.x * 4 + w;
    int b = g / R;

    short* xb = buf[w];
    float* ss = ssx[w];

    // ---- build x0 [32][16] bf16 (cols 16..31 zero-padded for K=32 MFMA) ----
    {
        int j = lane >> 1, half = lane & 1;
        float v[8];
        if (half == 0) {
            v[0] = xs[g*32 + j];
            #pragma unroll
            for (int kk = 0; kk < 7; ++kk) v[1+kk] = pe[b*480 + j*15 + kk];
        } else {
            #pragma unroll
            for (int kk = 0; kk < 8; ++kk) v[kk] = pe[b*480 + j*15 + 7 + kk];
        }
        short8 px;
        #pragma unroll
        for (int kk = 0; kk < 8; ++kk) px[kk] = f2bf(v[kk]);
        *(short8*)&xb[j*136 + half*8] = px;
        *(short8*)&xb[j*136 + 16 + half*8] = (short8){0,0,0,0,0,0,0,0};
    }

    const short* wt1 = ws;
    const short* wt2 = ws + 4608;
    const short* wt3 = ws + 23040;

    // ================= layer 1 (K=16 padded to 32) =================
    {
        gemm_ht<1,9,8>(xb, wt1, ss, c, q);
        f32x4 acc[8][2]; float rden[4][2];
        agg12(xb, ss, c, q, acc, rden);
        trans_phase(acc, rden, b1, xb, c, q);
    }
    // ================= layer 2 (K=128) =============================
    {
        gemm_ht<4,9,8>(xb, wt2, ss, c, q);
        f32x4 acc[8][2]; float rden[4][2];
        agg12(xb, ss, c, q, acc, rden);
        trans_phase(acc, rden, b2, xb, c, q);
    }
    // ================= layer 3 (packed 24+8, P-as-A agg, mean) =====
    {
        gemm3_ht(xb, wt3, ss, c, q, lane);
        agg3_mean(xb, ss, b3, ss, c, q);   // mcol aliases ss[0..23]
    }
    // ---- epilogue: out[g] = mcol @ lin_w + lin_b (f32) ----
    {
        float o = lb[lane];
        #pragma unroll
        for (int cc = 0; cc < 24; ++cc)
            o = fmaf(ss[cc], LW[cc*64 + lane], o);
        out[g*64 + lane] = o;
    }
}

extern "C" void kernel_launch(void* const* d_in, const int* in_sizes, int n_in,
                              void* d_out, int out_size, void* d_ws, size_t ws_size,
                              hipStream_t stream) {
    const float* xs  = (const float*)d_in[0];
    const float* pe  = (const float*)d_in[1];
    const float* W1  = (const float*)d_in[2];
    const float* as1 = (const float*)d_in[3];
    const float* ad1 = (const float*)d_in[4];
    const float* b1  = (const float*)d_in[5];
    const float* W2  = (const float*)d_in[6];
    const float* as2 = (const float*)d_in[7];
    const float* ad2 = (const float*)d_in[8];
    const float* b2  = (const float*)d_in[9];
    const float* W3  = (const float*)d_in[10];
    const float* as3 = (const float*)d_in[11];
    const float* ad3 = (const float*)d_in[12];
    const float* b3  = (const float*)d_in[13];
    const float* LW  = (const float*)d_in[14];
    const float* lb  = (const float*)d_in[15];
    float* o = (float*)d_out;
    short* ws = (short*)d_ws;

    int G = in_sizes[0] / 32;       // B*R graphs (16384)
    int B = in_sizes[1] / 480;      // pos_enc = B*32*15
    int R = G / B;

    build_wt<<<dim3(106), dim3(256), 0, stream>>>(W1, as1, ad1, W2, as2, ad2,
                                                  W3, as3, ad3, ws);
    gat_mfma<<<dim3(G/4), dim3(256), 0, stream>>>(xs, pe, ws, b1, b2, b3, LW, lb, o, R);
}